// Round 1
// baseline (193918.542 us; speedup 1.0000x reference)
//
#include <hip/hip_runtime.h>
#include <math.h>

// Problem constants (fixed by the reference)
#define NB     16       // batch
#define NW     64       // net width W
#define NK     1024     // number of vis blocks
#define NPX    1024     // NPIX
#define NVIS_  65536
#define NSLICE 64       // workgroups = P-slices
#define SLICE  16       // pixels per WG (NSLICE*SLICE = NPX)
#define TPB    256

// Cross-WG data must be device-coherent (per-XCD L2s are not coherent):
#define AG_LDF(p)    __hip_atomic_load((p), __ATOMIC_RELAXED, __HIP_MEMORY_SCOPE_AGENT)
#define AG_STF(p,v)  __hip_atomic_store((p), (v), __ATOMIC_RELAXED, __HIP_MEMORY_SCOPE_AGENT)

// ws layout in 32-bit words:
//   0            : root barrier counter
//   32*(g+1)     : leaf barrier counters g=0..7 (separate cache lines)
//   288..303     : per-iteration global-max slots (float bits, atomicMax)
//   512..2559    : rbuf   [NB][NW][2] f32
//   4096..135167 : part   [NSLICE][NB][NW][2] f32
//   262144..     : tau    [NB][NK][NW] f32 (private per sequencer WG)
#define WS_GMAX 288
#define WS_RBUF 512
#define WS_PART 4096
#define WS_TAU  262144

__global__ void robbi_init(unsigned* ws) {
  for (int i = threadIdx.x; i < 512; i += blockDim.x)
    __hip_atomic_store(ws + i, 0u, __ATOMIC_RELAXED, __HIP_MEMORY_SCOPE_AGENT);
}

// Monotonic tree barrier: 8 leaves x 8 WGs -> root. n is the 1-based barrier
// ordinal; barrier n done when root == 8n. Counters zeroed by robbi_init each call.
__device__ __forceinline__ void gbar(unsigned* root, unsigned* leaf, unsigned n) {
  __syncthreads();   // also drains this WG's outstanding AGENT stores (vmcnt)
  if (threadIdx.x == 0) {
    unsigned old = __hip_atomic_fetch_add(leaf, 1u, __ATOMIC_ACQ_REL, __HIP_MEMORY_SCOPE_AGENT);
    if ((old & 7u) == 7u)
      __hip_atomic_fetch_add(root, 1u, __ATOMIC_ACQ_REL, __HIP_MEMORY_SCOPE_AGENT);
    const unsigned target = 8u * n;
    while (__hip_atomic_load(root, __ATOMIC_ACQUIRE, __HIP_MEMORY_SCOPE_AGENT) < target)
      __builtin_amdgcn_s_sleep(4);
  }
  __syncthreads();
}

__global__ __launch_bounds__(TPB, 1) void robbi_persistent(
    const float* __restrict__ y_re, const float* __restrict__ y_im,
    const float* __restrict__ H_re, const float* __restrict__ H_im,
    const float* __restrict__ Ew, const float* __restrict__ Eb,
    const float* __restrict__ Uw, const float* __restrict__ Ub,
    const float* __restrict__ Mw, const float* __restrict__ Mb,
    const float* __restrict__ thr_p, const int* __restrict__ niter_p,
    float* __restrict__ out, float* ws) {
  const int s = blockIdx.x;        // slice id
  const int t = threadIdx.x;
  unsigned* wsu  = (unsigned*)ws;
  unsigned* root = wsu;
  unsigned* leaf = wsu + 32 * ((s & 7) + 1);
  unsigned* gmax = wsu + WS_GMAX;
  float* rbuf = ws + WS_RBUF;
  float* part = ws + WS_PART;
  float* tau  = ws + WS_TAU;

  // LDS (~71 KB)
  __shared__ float xs[NB * 34];          // x slice: [b][2j+c], pad 34 (b64-aligned)
  __shared__ float hT[NW * 34];          // H tile:  [w][2j+c], pad 34
  __shared__ float rs[NB * 132];         // r:       [b][2w+c], pad 132
  __shared__ float wE[NW * 65], wU[NW * 65], wM[NW * 65];
  __shared__ float bE[NW], bU[NW], bM[NW];
  __shared__ float red[512];
  __shared__ float r2s[NW], tps[NW], hts[NW];

  const int p0 = s * SLICE;
  const float thr = *thr_p;
  const int niter = *niter_p;

  if (s < NB) {  // sequencer WGs cache the MLP weights in LDS
    for (int i = t; i < NW * NW; i += TPB) {
      int r = i >> 6, c = i & 63;
      wE[r * 65 + c] = Ew[i]; wU[r * 65 + c] = Uw[i]; wM[r * 65 + c] = Mw[i];
    }
    if (t < NW) { bE[t] = Eb[t]; bU[t] = Ub[t]; bM[t] = Mb[t]; }
  }

  // ---- x0 = sum_k y_k @ H_k for this WG's pixel slice (no conj) ----
  {
    const int b = t >> 4, j = t & 15;
    const float* hr = H_re + p0 + j;
    const float* hi = H_im + p0 + j;
    const float* yr = y_re + b * NVIS_;
    const float* yi = y_im + b * NVIS_;
    float ar = 0.f, ai = 0.f;
#pragma unroll 4
    for (int kw = 0; kw < NVIS_; ++kw) {
      float Yr = yr[kw], Yi = yi[kw];
      float Hr = hr[(size_t)kw * NPX], Hi = hi[(size_t)kw * NPX];
      ar += Yr * Hr - Yi * Hi;
      ai += Yr * Hi + Yi * Hr;
    }
    xs[b * 34 + 2 * j]     = ar;
    xs[b * 34 + 2 * j + 1] = ai;
  }
  __syncthreads();

  unsigned barn = 0;

  for (int iter = 0; iter < niter; ++iter) {
    for (int k = 0; k < NK; ++k) {
      // ---- stage H tile for block k (used by phase A and phase C) ----
      {
        int w = t >> 2, q = t & 3;
        const float* bR = H_re + (size_t)(k * NW + w) * NPX + p0 + 4 * q;
        const float* bI = H_im + (size_t)(k * NW + w) * NPX + p0 + 4 * q;
        float4 r4 = *(const float4*)bR;
        float4 i4 = *(const float4*)bI;
        int c0 = w * 34 + 8 * q;
        hT[c0 + 0] = r4.x; hT[c0 + 1] = i4.x;
        hT[c0 + 2] = r4.y; hT[c0 + 3] = i4.y;
        hT[c0 + 4] = r4.z; hT[c0 + 5] = i4.z;
        hT[c0 + 6] = r4.w; hT[c0 + 7] = i4.w;
      }
      __syncthreads();

      // ---- phase A: partial z[b][w] = sum_{p in slice} x * conj(H) ----
      {
        int w = t & 63, wid = t >> 6;
#pragma unroll
        for (int q = 0; q < 4; ++q) {
          int b = 4 * q + wid;   // uniform per wave -> xs reads broadcast
          float zr = 0.f, zi = 0.f;
#pragma unroll
          for (int j = 0; j < SLICE; ++j) {
            float xr = xs[b * 34 + 2 * j], xi = xs[b * 34 + 2 * j + 1];
            float hr = hT[w * 34 + 2 * j], hi = hT[w * 34 + 2 * j + 1];
            zr += xr * hr + xi * hi;
            zi += xi * hr - xr * hi;
          }
          float* pp = part + ((s * NB + b) * NW + w) * 2;
          AG_STF(pp, zr); AG_STF(pp + 1, zi);
        }
      }
      ++barn; gbar(root, leaf, barn);

      // ---- phase B: sequencer WG b reduces z, runs gating MLP, emits r ----
      if (s < NB) {
        const int b = s;
        int w = t & 63, q = t >> 6;
        float aR = 0.f, aI = 0.f;
#pragma unroll
        for (int i2 = 0; i2 < 16; ++i2) {
          int sl = q * 16 + i2;
          const float* pp = part + ((sl * NB + b) * NW + w) * 2;
          aR += AG_LDF(pp); aI += AG_LDF(pp + 1);
        }
        red[q * 64 + w] = aR; red[256 + q * 64 + w] = aI;
        __syncthreads();
        float ybr = 0.f, ybi = 0.f, zr = 0.f, zi = 0.f;
        if (t < 64) {
          zr = red[t] + red[64 + t] + red[128 + t] + red[192 + t];
          zi = red[256 + t] + red[320 + t] + red[384 + t] + red[448 + t];
          ybr = y_re[b * NVIS_ + k * NW + t];
          ybi = y_im[b * NVIS_ + k * NW + t];
          float dr = ybr - zr, di = ybi - zi;
          r2s[t] = dr * dr + di * di;
          tps[t] = (iter == 0) ? 0.f : tau[(b * NK + k) * NW + t];
        }
        __syncthreads();
        if (t < 64) {
          float a = bE[t];
#pragma unroll 8
          for (int j = 0; j < 64; ++j) a += wE[t * 65 + j] * r2s[j];
          hts[t] = 1.f / (1.f + expf(-a));
        }
        __syncthreads();
        if (t < 64) {
          float a = bU[t] + bM[t];
#pragma unroll 8
          for (int j = 0; j < 64; ++j) a += wU[t * 65 + j] * hts[j] + wM[t * 65 + j] * tps[j];
          float wn = fmaxf(a, 0.f);
          tau[(b * NK + k) * NW + t] = wn;
          float* rp = rbuf + (b * NW + t) * 2;
          AG_STF(rp,     ybr - zr * wn);
          AG_STF(rp + 1, ybi - zi * wn);
        }
      }
      ++barn; gbar(root, leaf, barn);

      // ---- phase C: x[:, slice] += (1/W) * r @ H (no conj) ----
      {
#pragma unroll
        for (int u = 0; u < 8; ++u) {
          int f = t * 8 + u;                 // 0..2047
          rs[(f >> 7) * 132 + (f & 127)] = AG_LDF(rbuf + f);
        }
        __syncthreads();
        int b = t >> 4, j = t & 15;
        float aR = 0.f, aI = 0.f;
#pragma unroll 8
        for (int w = 0; w < NW; ++w) {
          float rr = rs[b * 132 + 2 * w], ri = rs[b * 132 + 2 * w + 1];
          float hr = hT[w * 34 + 2 * j], hi = hT[w * 34 + 2 * j + 1];
          aR += rr * hr - ri * hi;
          aI += rr * hi + ri * hr;
        }
        xs[b * 34 + 2 * j]     += aR * (1.f / NW);
        xs[b * 34 + 2 * j + 1] += aI * (1.f / NW);
      }
      __syncthreads();   // xs/hT settled before next tile overwrite
    }

    // ---- global soft-threshold: x = sgn(x) * relu(|x| - thr * max|x|) ----
    {
      int b = t >> 4, j = t & 15;
      float xr = xs[b * 34 + 2 * j], xi = xs[b * 34 + 2 * j + 1];
      float ax = sqrtf(xr * xr + xi * xi);
      red[t] = ax;
      __syncthreads();
      for (int off = 128; off > 0; off >>= 1) {
        if (t < off) red[t] = fmaxf(red[t], red[t + off]);
        __syncthreads();
      }
      if (t == 0)
        __hip_atomic_fetch_max(gmax + iter, __float_as_uint(red[0]),
                               __ATOMIC_RELAXED, __HIP_MEMORY_SCOPE_AGENT);
      ++barn; gbar(root, leaf, barn);
      float gm = __uint_as_float(__hip_atomic_load(gmax + iter, __ATOMIC_RELAXED,
                                                   __HIP_MEMORY_SCOPE_AGENT));
      float mag = fmaxf(ax - thr * gm, 0.f);
      float sc = (ax > 0.f) ? (mag / ax) : 0.f;
      xs[b * 34 + 2 * j]     = xr * sc;
      xs[b * 34 + 2 * j + 1] = xi * sc;
      if (iter == niter - 1)
        out[b * NPX + p0 + j] = mag;     // |x| after final threshold
      __syncthreads();
    }
  }

  if (niter <= 0) {  // defensive: output |x0|
    int b = t >> 4, j = t & 15;
    float xr = xs[b * 34 + 2 * j], xi = xs[b * 34 + 2 * j + 1];
    out[b * NPX + p0 + j] = sqrtf(xr * xr + xi * xi);
  }
}

extern "C" void kernel_launch(void* const* d_in, const int* in_sizes, int n_in,
                              void* d_out, int out_size, void* d_ws, size_t ws_size,
                              hipStream_t stream) {
  const float* y_re = (const float*)d_in[0];
  const float* y_im = (const float*)d_in[1];
  const float* H_re = (const float*)d_in[2];
  const float* H_im = (const float*)d_in[3];
  const float* Ew   = (const float*)d_in[4];
  const float* Eb   = (const float*)d_in[5];
  const float* Uw   = (const float*)d_in[6];
  const float* Ub   = (const float*)d_in[7];
  const float* Mw   = (const float*)d_in[8];
  const float* Mb   = (const float*)d_in[9];
  const float* thr  = (const float*)d_in[10];
  const int*  niter = (const int*)d_in[11];

  robbi_init<<<1, 128, 0, stream>>>((unsigned*)d_ws);
  robbi_persistent<<<NSLICE, TPB, 0, stream>>>(
      y_re, y_im, H_re, H_im, Ew, Eb, Uw, Ub, Mw, Mb, thr, niter,
      (float*)d_out, (float*)d_ws);
}

// Round 2
// 76489.978 us; speedup vs baseline: 2.5352x; 2.5352x over previous
//
#include <hip/hip_runtime.h>
#include <math.h>

// Problem constants (fixed by the reference)
#define NB     16       // batch
#define NW     64       // net width W
#define NK     1024     // number of vis blocks
#define NPX    1024     // NPIX
#define NVIS_  65536
#define MEMB   8        // WGs per batch group
#define PXM    128      // pixels per member
#define TPB    256
#define NWG    128      // total workgroups

#define AG_LDF(p)    __hip_atomic_load((p), __ATOMIC_RELAXED, __HIP_MEMORY_SCOPE_AGENT)
#define AG_STF(p,v)  __hip_atomic_store((p), (v), __ATOMIC_RELAXED, __HIP_MEMORY_SCOPE_AGENT)

// ws layout (32-bit words):
//   0           : global barrier root
//   32*(x+1)    : global barrier leaves, x=0..7 (per XCD slot)
//   288..303    : per-iteration global-max slots (float bits)
//   320+32*b    : per-group step counters, b=0..15
//   1024        : part [2][NB][MEMB][NW][2] f32   (128 KB)
//   36864       : x0p  [NWG][NB][PXM][2] f32      (2 MB)
//   589824      : tau  [NB][NK][NW] f32           (4 MB)
#define WS_GMAX  288
#define WS_GRP   320
#define WS_PART  1024
#define WS_X0P   36864
#define WS_TAU   589824

__global__ void robbi_init(unsigned* ws) {
  for (int i = threadIdx.x; i < 1024; i += blockDim.x)
    __hip_atomic_store(ws + i, 0u, __ATOMIC_RELAXED, __HIP_MEMORY_SCOPE_AGENT);
}

// Group barrier: 8 members, monotonic counter, target = 8*step_ordinal.
__device__ __forceinline__ void gbar_grp(unsigned* ctr, unsigned target) {
  __syncthreads();   // all waves drain vmcnt before any lane arrives
  if (threadIdx.x == 0) {
    __hip_atomic_fetch_add(ctr, 1u, __ATOMIC_ACQ_REL, __HIP_MEMORY_SCOPE_AGENT);
    while (__hip_atomic_load(ctr, __ATOMIC_ACQUIRE, __HIP_MEMORY_SCOPE_AGENT) < target)
      __builtin_amdgcn_s_sleep(1);
  }
  __syncthreads();
}

// Global barrier: 8 leaves (by blockIdx%8), 16 WGs per leaf; done when root == 8*n.
__device__ __forceinline__ void gbar_all(unsigned* root, unsigned* leaf, unsigned n) {
  __syncthreads();
  if (threadIdx.x == 0) {
    unsigned old = __hip_atomic_fetch_add(leaf, 1u, __ATOMIC_ACQ_REL, __HIP_MEMORY_SCOPE_AGENT);
    if ((old & 15u) == 15u)
      __hip_atomic_fetch_add(root, 1u, __ATOMIC_ACQ_REL, __HIP_MEMORY_SCOPE_AGENT);
    const unsigned target = 8u * n;
    while (__hip_atomic_load(root, __ATOMIC_ACQUIRE, __HIP_MEMORY_SCOPE_AGENT) < target)
      __builtin_amdgcn_s_sleep(4);
  }
  __syncthreads();
}

__global__ __launch_bounds__(TPB) void robbi_persistent(
    const float* __restrict__ y_re, const float* __restrict__ y_im,
    const float* __restrict__ H_re, const float* __restrict__ H_im,
    const float* __restrict__ Ew, const float* __restrict__ Eb,
    const float* __restrict__ Uw, const float* __restrict__ Ub,
    const float* __restrict__ Mw, const float* __restrict__ Mb,
    const float* __restrict__ thr_p, const int* __restrict__ niter_p,
    float* __restrict__ out, float* ws) {
  const int bid = blockIdx.x;
  const int t = threadIdx.x;
  // group mapping: 8 members of a group share blockIdx % 8 (same XCD if round-robin)
  const int xcd = bid & 7, gi = bid >> 3;
  const int b = xcd + 8 * (gi >> 3);   // batch 0..15
  const int m = gi & 7;                // member 0..7

  unsigned* wsu   = (unsigned*)ws;
  unsigned* root  = wsu;
  unsigned* leaf  = wsu + 32 * (xcd + 1);
  unsigned* gmax  = wsu + WS_GMAX;
  unsigned* grpc  = wsu + WS_GRP + 32 * b;
  float* part = ws + WS_PART;
  float* x0p  = ws + WS_X0P;
  float* tau  = ws + WS_TAU;

  __shared__ float wE[NW * 65], wU[NW * 65], wM[NW * 65];
  __shared__ float bE[NW], bU[NW], bM[NW];
  __shared__ float xs[PXM * 2];
  __shared__ float zred[512];
  __shared__ float accm[256];
  __shared__ float r2s[NW], tps[NW], hts[NW];
  __shared__ float zs[2 * NW], ybs[2 * NW], rs[2 * NW];
  __shared__ float red8[2048];
  __shared__ float ysr[2048], ysi[2048];
  __shared__ float axs[PXM];

  const float thr = *thr_p;
  const int niter = *niter_p;

  // ---- cache MLP weights (row-padded 65) ----
  for (int i = t; i < NW * NW; i += TPB) {
    int r = i >> 6, c = i & 63;
    wE[r * 65 + c] = Ew[i]; wU[r * 65 + c] = Uw[i]; wM[r * 65 + c] = Mw[i];
  }
  if (t < NW) { bE[t] = Eb[t]; bU[t] = Ub[t]; bM[t] = Mb[t]; }

  const int wsub = t >> 5;        // 0..7
  const int g5   = t & 31;        // 0..31
  const int p4   = 4 * g5;        // pixel quad base within 128-px slice

  // ---- x0 stage 1: non-redundant partial GEMM over (kw-chunk, pixel-slice) ----
  {
    const int kwc = bid >> 3, ps = bid & 7;
    float ar[2][4], ai[2][4];
#pragma unroll
    for (int h = 0; h < 2; ++h)
#pragma unroll
      for (int j = 0; j < 4; ++j) { ar[h][j] = 0.f; ai[h][j] = 0.f; }
    for (int slab = 0; slab < 32; ++slab) {
      const int kw0 = kwc * 4096 + slab * 128;
      for (int e = t; e < 2048; e += TPB) {
        int bb = e >> 7, j = e & 127;
        ysr[e] = y_re[bb * NVIS_ + kw0 + j];
        ysi[e] = y_im[bb * NVIS_ + kw0 + j];
      }
      __syncthreads();
      for (int j = 0; j < 128; ++j) {
        const size_t off = (size_t)(kw0 + j) * NPX + ps * PXM + p4;
        float4 h4r = *(const float4*)(H_re + off);
        float4 h4i = *(const float4*)(H_im + off);
#pragma unroll
        for (int h = 0; h < 2; ++h) {
          int bb = wsub + 8 * h;
          float yr = ysr[bb * 128 + j], yi = ysi[bb * 128 + j];
          ar[h][0] += yr * h4r.x - yi * h4i.x; ai[h][0] += yr * h4i.x + yi * h4r.x;
          ar[h][1] += yr * h4r.y - yi * h4i.y; ai[h][1] += yr * h4i.y + yi * h4r.y;
          ar[h][2] += yr * h4r.z - yi * h4i.z; ai[h][2] += yr * h4i.z + yi * h4r.z;
          ar[h][3] += yr * h4r.w - yi * h4i.w; ai[h][3] += yr * h4i.w + yi * h4r.w;
        }
      }
      __syncthreads();
    }
#pragma unroll
    for (int h = 0; h < 2; ++h) {
      int bb = wsub + 8 * h;
#pragma unroll
      for (int j = 0; j < 4; ++j) {
        float* pp = x0p + ((size_t)(bid * NB + bb) * PXM + p4 + j) * 2;
        AG_STF(pp, ar[h][j]); AG_STF(pp + 1, ai[h][j]);
      }
    }
  }
  gbar_all(root, leaf, 1);

  // ---- x0 stage 2: reduce the 16 kw-chunks for this member's slice ----
  {
    int p = t & 127, c = t >> 7;
    float s = 0.f;
    for (int kwc = 0; kwc < 16; ++kwc)
      s += AG_LDF(x0p + ((size_t)((kwc * 8 + m) * NB + b) * PXM + p) * 2 + c);
    xs[p * 2 + c] = s;
  }
  __syncthreads();

  if (niter <= 0) {
    if (t < PXM) {
      float xr = xs[2 * t], xi = xs[2 * t + 1];
      out[b * NPX + m * PXM + t] = sqrtf(xr * xr + xi * xi);
    }
    return;
  }

  for (int iter = 0; iter < niter; ++iter) {
    for (int k = 0; k < NK; ++k) {
      const int buf = k & 1;
      // x quad in regs (stable: previous C/threshold ended with __syncthreads)
      float xr0 = xs[p4 * 2],     xi0 = xs[p4 * 2 + 1];
      float xr1 = xs[p4 * 2 + 2], xi1 = xs[p4 * 2 + 3];
      float xr2 = xs[p4 * 2 + 4], xi2 = xs[p4 * 2 + 5];
      float xr3 = xs[p4 * 2 + 6], xi3 = xs[p4 * 2 + 7];

      // H tile for this member: rows w = 8i+wsub, pixel quad p4 (held in regs,
      // used by BOTH phase A and phase C -> H read exactly once per step)
      float4 hr[8], hi[8];
      const size_t rb = (size_t)(k * NW + wsub) * NPX + m * PXM + p4;
#pragma unroll
      for (int i = 0; i < 8; ++i) {
        hr[i] = *(const float4*)(H_re + rb + (size_t)i * 8 * NPX);
        hi[i] = *(const float4*)(H_im + rb + (size_t)i * 8 * NPX);
      }

      // ---- phase A: zpart[w] = sum_{4 px} x*conj(H); half-wave reduce ----
      float zpr[8], zpi[8];
#pragma unroll
      for (int i = 0; i < 8; ++i) {
        float zr = xr0 * hr[i].x + xi0 * hi[i].x + xr1 * hr[i].y + xi1 * hi[i].y
                 + xr2 * hr[i].z + xi2 * hi[i].z + xr3 * hr[i].w + xi3 * hi[i].w;
        float zi = xi0 * hr[i].x - xr0 * hi[i].x + xi1 * hr[i].y - xr1 * hi[i].y
                 + xi2 * hr[i].z - xr2 * hi[i].z + xi3 * hr[i].w - xr3 * hi[i].w;
#pragma unroll
        for (int msk = 16; msk >= 1; msk >>= 1) {
          zr += __shfl_xor(zr, msk);
          zi += __shfl_xor(zi, msk);
        }
        zpr[i] = zr; zpi[i] = zi;
      }
      if (g5 == 0) {
#pragma unroll
        for (int i = 0; i < 8; ++i) {
          float* pp = part + (size_t)(((buf * NB + b) * MEMB + m) * NW + 8 * i + wsub) * 2;
          AG_STF(pp, zpr[i]); AG_STF(pp + 1, zpi[i]);
        }
      }

      gbar_grp(grpc, 8u * (unsigned)(iter * NK + k + 1));

      // ---- phase B (computed redundantly by every member; no 2nd barrier) ----
      {
        const int q = t >> 6, w = t & 63;
        float zr = 0.f, zi = 0.f;
#pragma unroll
        for (int e = 0; e < 2; ++e) {
          int mm = 2 * q + e;
          const float* pp = part + (size_t)(((buf * NB + b) * MEMB + mm) * NW + w) * 2;
          zr += AG_LDF(pp); zi += AG_LDF(pp + 1);
        }
        zred[(q * 64 + w) * 2] = zr; zred[(q * 64 + w) * 2 + 1] = zi;
        __syncthreads();
        if (t < NW) {
          float szr = zred[t * 2] + zred[(64 + t) * 2] + zred[(128 + t) * 2] + zred[(192 + t) * 2];
          float szi = zred[t * 2 + 1] + zred[(64 + t) * 2 + 1] + zred[(128 + t) * 2 + 1] + zred[(192 + t) * 2 + 1];
          float ybr = y_re[b * NVIS_ + k * NW + t];
          float ybi = y_im[b * NVIS_ + k * NW + t];
          float dr = ybr - szr, di = ybi - szi;
          r2s[t] = dr * dr + di * di;
          tps[t] = (iter == 0) ? 0.f : AG_LDF(tau + (size_t)(b * NK + k) * NW + t);
          zs[2 * t] = szr; zs[2 * t + 1] = szi;
          ybs[2 * t] = ybr; ybs[2 * t + 1] = ybi;
        }
        __syncthreads();
        float a = 0.f;
#pragma unroll
        for (int jj = 0; jj < 16; ++jj) { int j = q * 16 + jj; a += wE[w * 65 + j] * r2s[j]; }
        accm[q * 64 + w] = a;
        __syncthreads();
        if (t < NW) {
          float sE = bE[t] + accm[t] + accm[64 + t] + accm[128 + t] + accm[192 + t];
          hts[t] = 1.f / (1.f + __expf(-sE));
        }
        __syncthreads();
        a = 0.f;
#pragma unroll
        for (int jj = 0; jj < 16; ++jj) {
          int j = q * 16 + jj;
          a += wU[w * 65 + j] * hts[j] + wM[w * 65 + j] * tps[j];
        }
        accm[q * 64 + w] = a;
        __syncthreads();
        if (t < NW) {
          float wn = fmaxf(bU[t] + bM[t] + accm[t] + accm[64 + t] + accm[128 + t] + accm[192 + t], 0.f);
          if (m == 0) AG_STF(tau + (size_t)(b * NK + k) * NW + t, wn);
          rs[2 * t]     = ybs[2 * t]     - zs[2 * t]     * wn;
          rs[2 * t + 1] = ybs[2 * t + 1] - zs[2 * t + 1] * wn;
        }
        __syncthreads();
      }

      // ---- phase C: x[px] += (1/W) * sum_w r[w]*H[w,px] (H from regs) ----
      {
        float cr0 = 0.f, ci0 = 0.f, cr1 = 0.f, ci1 = 0.f;
        float cr2 = 0.f, ci2 = 0.f, cr3 = 0.f, ci3 = 0.f;
#pragma unroll
        for (int i = 0; i < 8; ++i) {
          float rr = rs[(8 * i + wsub) * 2], ri = rs[(8 * i + wsub) * 2 + 1];
          cr0 += rr * hr[i].x - ri * hi[i].x; ci0 += rr * hi[i].x + ri * hr[i].x;
          cr1 += rr * hr[i].y - ri * hi[i].y; ci1 += rr * hi[i].y + ri * hr[i].y;
          cr2 += rr * hr[i].z - ri * hi[i].z; ci2 += rr * hi[i].z + ri * hr[i].z;
          cr3 += rr * hr[i].w - ri * hi[i].w; ci3 += rr * hi[i].w + ri * hr[i].w;
        }
        float4* r8 = (float4*)red8;
        r8[(wsub * 32 + g5) * 2]     = make_float4(cr0, ci0, cr1, ci1);
        r8[(wsub * 32 + g5) * 2 + 1] = make_float4(cr2, ci2, cr3, ci3);
        __syncthreads();
        int p = t & 127, c = t >> 7;
        float ssum = 0.f;
#pragma unroll
        for (int w2 = 0; w2 < 8; ++w2)
          ssum += red8[(w2 * 32 + (p >> 2)) * 8 + (p & 3) * 2 + c];
        xs[p * 2 + c] += ssum * (1.f / NW);
        __syncthreads();
      }
    }

    // ---- global soft-threshold ----
    {
      float ax = 0.f;
      int p = t & 127;
      if (t < PXM) {
        float xr = xs[2 * p], xi = xs[2 * p + 1];
        ax = sqrtf(xr * xr + xi * xi);
        axs[p] = ax;
      }
      __syncthreads();
      for (int off = 64; off > 0; off >>= 1) {
        if (t < off) axs[t] = fmaxf(axs[t], axs[t + off]);
        __syncthreads();
      }
      if (t == 0)
        __hip_atomic_fetch_max(gmax + iter, __float_as_uint(axs[0]),
                               __ATOMIC_RELAXED, __HIP_MEMORY_SCOPE_AGENT);
      gbar_all(root, leaf, 2 + iter);
      float gm = __uint_as_float(__hip_atomic_load(gmax + iter, __ATOMIC_RELAXED,
                                                   __HIP_MEMORY_SCOPE_AGENT));
      if (t < PXM) {
        float mag = fmaxf(ax - thr * gm, 0.f);
        float sc = (ax > 0.f) ? (mag / ax) : 0.f;
        xs[2 * p] *= sc; xs[2 * p + 1] *= sc;
        if (iter == niter - 1) out[b * NPX + m * PXM + p] = mag;
      }
      __syncthreads();
    }
  }
}

extern "C" void kernel_launch(void* const* d_in, const int* in_sizes, int n_in,
                              void* d_out, int out_size, void* d_ws, size_t ws_size,
                              hipStream_t stream) {
  const float* y_re = (const float*)d_in[0];
  const float* y_im = (const float*)d_in[1];
  const float* H_re = (const float*)d_in[2];
  const float* H_im = (const float*)d_in[3];
  const float* Ew   = (const float*)d_in[4];
  const float* Eb   = (const float*)d_in[5];
  const float* Uw   = (const float*)d_in[6];
  const float* Ub   = (const float*)d_in[7];
  const float* Mw   = (const float*)d_in[8];
  const float* Mb   = (const float*)d_in[9];
  const float* thr  = (const float*)d_in[10];
  const int*  niter = (const int*)d_in[11];

  robbi_init<<<1, 256, 0, stream>>>((unsigned*)d_ws);
  robbi_persistent<<<NWG, TPB, 0, stream>>>(
      y_re, y_im, H_re, H_im, Ew, Eb, Uw, Ub, Mw, Mb, thr, niter,
      (float*)d_out, (float*)d_ws);
}

// Round 4
// 75157.129 us; speedup vs baseline: 2.5802x; 1.0177x over previous
//
#include <hip/hip_runtime.h>
#include <math.h>

// Problem constants (fixed by the reference)
#define NB     16       // batch
#define NW     64       // net width W
#define NK     1024     // number of vis blocks
#define NPX    1024     // NPIX
#define NVIS_  65536
#define MEMB   8        // WGs per batch group
#define PXM    128      // pixels per member
#define TPB    256
#define NWG    128      // total workgroups

#define AG_LDF(p)    __hip_atomic_load((p), __ATOMIC_RELAXED, __HIP_MEMORY_SCOPE_AGENT)
#define AG_STF(p,v)  __hip_atomic_store((p), (v), __ATOMIC_RELAXED, __HIP_MEMORY_SCOPE_AGENT)

// ws layout (32-bit words):
//   0           : global barrier root
//   32*(x+1)    : global barrier leaves, x=0..7 (per XCD slot)
//   288..303    : per-iteration global-max slots (float bits)
//   320+32*b    : per-group step counters, b=0..15
//   1024        : part [2][NB][MEMB][NW][2] f32   (128 KB)
//   36864       : x0p  [NWG][NB][PXM][2] f32      (2 MB)
//   589824      : tau  [NB][NK][NW] f32           (4 MB)
#define WS_GMAX  288
#define WS_GRP   320
#define WS_PART  1024
#define WS_X0P   36864
#define WS_TAU   589824

__global__ void robbi_init(unsigned* ws) {
  for (int i = threadIdx.x; i < 1024; i += blockDim.x)
    __hip_atomic_store(ws + i, 0u, __ATOMIC_RELAXED, __HIP_MEMORY_SCOPE_AGENT);
}

// Global barrier (used only at x0 handoff and per-iteration threshold).
__device__ __forceinline__ void gbar_all(unsigned* root, unsigned* leaf, unsigned n) {
  __syncthreads();
  if (threadIdx.x == 0) {
    unsigned old = __hip_atomic_fetch_add(leaf, 1u, __ATOMIC_ACQ_REL, __HIP_MEMORY_SCOPE_AGENT);
    if ((old & 15u) == 15u)
      __hip_atomic_fetch_add(root, 1u, __ATOMIC_ACQ_REL, __HIP_MEMORY_SCOPE_AGENT);
    const unsigned target = 8u * n;
    while (__hip_atomic_load(root, __ATOMIC_ACQUIRE, __HIP_MEMORY_SCOPE_AGENT) < target)
      __builtin_amdgcn_s_sleep(4);
  }
  __syncthreads();
}

// One Gauss-Seidel step. HRC/HIC = current H tile (regs), HRN/HIN = prefetch slot.
// Sync discipline:
//   posts -> [compiler fence] -> H prefetch -> s_waitcnt vmcnt(16) -> raw barrier
//   (vmcnt retires in issue order: waiting to <=16 drains the posts and anything
//   older while the 16 prefetch loads stay in flight across the barrier)
// NOTE: all macro-locals end in '_' — the KARG expansion may reference the
// caller's loop variable, so no inner name may shadow it (R3 crash cause).
#define STEP_BODY(KARG, HRC, HIC, HRN, HIN)                                    \
  {                                                                            \
    const int k_ = (KARG);                                                     \
    const int buf_ = k_ & 1;                                                   \
    /* ---- phase A: zpart[w] = sum_{4 px} x*conj(H) (regs+LDS only) ---- */   \
    float4 xq0_ = *(const float4*)&xs[p4 * 2];                                 \
    float4 xq1_ = *(const float4*)&xs[p4 * 2 + 4];                             \
    float zpr_[8], zpi_[8];                                                    \
    _Pragma("unroll")                                                          \
    for (int i = 0; i < 8; ++i) {                                              \
      float zr = xq0_.x * HRC[i].x + xq0_.y * HIC[i].x                         \
               + xq0_.z * HRC[i].y + xq0_.w * HIC[i].y                         \
               + xq1_.x * HRC[i].z + xq1_.y * HIC[i].z                         \
               + xq1_.z * HRC[i].w + xq1_.w * HIC[i].w;                        \
      float zi = xq0_.y * HRC[i].x - xq0_.x * HIC[i].x                         \
               + xq0_.w * HRC[i].y - xq0_.z * HIC[i].y                         \
               + xq1_.y * HRC[i].z - xq1_.x * HIC[i].z                         \
               + xq1_.w * HRC[i].w - xq1_.z * HIC[i].w;                        \
      _Pragma("unroll")                                                        \
      for (int msk = 16; msk >= 1; msk >>= 1) {                                \
        zr += __shfl_xor(zr, msk); zi += __shfl_xor(zi, msk);                  \
      }                                                                        \
      zpr_[i] = zr; zpi_[i] = zi;                                              \
    }                                                                          \
    if (g5 == 0) {                                                             \
      _Pragma("unroll")                                                        \
      for (int i = 0; i < 8; ++i) {                                            \
        float* pp = part + (size_t)(((buf_ * NB + b) * MEMB + m) * NW + 8 * i + wsub) * 2; \
        AG_STF(pp, zpr_[i]); AG_STF(pp + 1, zpi_[i]);                          \
      }                                                                        \
    }                                                                          \
    asm volatile("" ::: "memory"); /* pin: posts BEFORE prefetch issue */      \
    /* ---- prefetch H for k_+1 (wraps to 0 at iteration end) ---- */          \
    {                                                                          \
      const int kn_ = (k_ + 1 < NK) ? (k_ + 1) : 0;                            \
      const size_t rbn_ = (size_t)(kn_ * NW + wsub) * NPX + m * PXM + p4;      \
      _Pragma("unroll")                                                        \
      for (int i = 0; i < 8; ++i) {                                            \
        HRN[i] = *(const float4*)(H_re + rbn_ + (size_t)i * 8 * NPX);          \
        HIN[i] = *(const float4*)(H_im + rbn_ + (size_t)i * 8 * NPX);          \
      }                                                                        \
    }                                                                          \
    /* ---- S1: group barrier; drain posts, keep prefetch in flight ---- */    \
    asm volatile("s_waitcnt vmcnt(16)" ::: "memory");                          \
    __builtin_amdgcn_s_barrier();                                              \
    if (t == 0) {                                                              \
      __hip_atomic_fetch_add(grpc, 1u, __ATOMIC_RELAXED, __HIP_MEMORY_SCOPE_AGENT); \
      const unsigned tgt_ = 8u * (unsigned)(iter * NK + k_ + 1);               \
      while (__hip_atomic_load(grpc, __ATOMIC_ACQUIRE, __HIP_MEMORY_SCOPE_AGENT) < tgt_) \
        __builtin_amdgcn_s_sleep(1);                                           \
    }                                                                          \
    __builtin_amdgcn_s_barrier();                                              \
    /* ---- phase B: single wave (lane = w), redundant per member ---- */      \
    if (t < 64) {                                                              \
      float zr = 0.f, zi = 0.f;                                                \
      _Pragma("unroll")                                                        \
      for (int mm = 0; mm < MEMB; ++mm) {                                      \
        const float* pp = part + (size_t)(((buf_ * NB + b) * MEMB + mm) * NW + t) * 2; \
        zr += AG_LDF(pp); zi += AG_LDF(pp + 1);                                \
      }                                                                        \
      float tpe = (iter == 0) ? 0.f : tpr;                                     \
      float dr = ypr_r - zr, di = ypr_i - zi;                                  \
      r2s[t] = dr * dr + di * di;                                              \
      tpl[t] = tpe;                                                            \
      float e = bE[t];                                                         \
      _Pragma("unroll 16")                                                     \
      for (int j = 0; j < 64; ++j) e += wE[t * 65 + j] * r2s[j];               \
      hts[t] = 1.f / (1.f + __expf(-e));                                       \
      float a = bU[t] + bM[t];                                                 \
      _Pragma("unroll 16")                                                     \
      for (int j = 0; j < 64; ++j)                                             \
        a += wU[t * 65 + j] * hts[j] + wM[t * 65 + j] * tpl[j];                \
      float wn = fmaxf(a, 0.f);                                                \
      if (m == 0) AG_STF(tau + (size_t)(b * NK + k_) * NW + t, wn);            \
      rs[2 * t] = ypr_r - zr * wn; rs[2 * t + 1] = ypr_i - zi * wn;            \
      /* prefetch y/tau for next step (retired by next S1's vmcnt(16)) */      \
      const int kn_ = (k_ + 1 < NK) ? (k_ + 1) : 0;                            \
      ypr_r = y_re[b * NVIS_ + kn_ * NW + t];                                  \
      ypr_i = y_im[b * NVIS_ + kn_ * NW + t];                                  \
      tpr = AG_LDF(tau + (size_t)(b * NK + kn_) * NW + t);                     \
    }                                                                          \
    /* ---- S2: rs visible to all waves ---- */                                \
    asm volatile("s_waitcnt lgkmcnt(0)" ::: "memory");                         \
    __builtin_amdgcn_s_barrier();                                              \
    /* ---- phase C: x[px] += (1/W) * sum_w r[w]*H[w,px] (H from regs) ---- */ \
    {                                                                          \
      float cr0 = 0.f, ci0 = 0.f, cr1 = 0.f, ci1 = 0.f;                        \
      float cr2 = 0.f, ci2 = 0.f, cr3 = 0.f, ci3 = 0.f;                        \
      _Pragma("unroll")                                                        \
      for (int i = 0; i < 8; ++i) {                                            \
        float rr = rs[(8 * i + wsub) * 2], ri = rs[(8 * i + wsub) * 2 + 1];    \
        cr0 += rr * HRC[i].x - ri * HIC[i].x; ci0 += rr * HIC[i].x + ri * HRC[i].x; \
        cr1 += rr * HRC[i].y - ri * HIC[i].y; ci1 += rr * HIC[i].y + ri * HRC[i].y; \
        cr2 += rr * HRC[i].z - ri * HIC[i].z; ci2 += rr * HIC[i].z + ri * HRC[i].z; \
        cr3 += rr * HRC[i].w - ri * HIC[i].w; ci3 += rr * HIC[i].w + ri * HRC[i].w; \
      }                                                                        \
      float4* r8_ = (float4*)red8;                                             \
      r8_[(wsub * 32 + g5) * 2]     = make_float4(cr0, ci0, cr1, ci1);         \
      r8_[(wsub * 32 + g5) * 2 + 1] = make_float4(cr2, ci2, cr3, ci3);         \
      asm volatile("s_waitcnt lgkmcnt(0)" ::: "memory");                       \
      __builtin_amdgcn_s_barrier();                                            \
      int p_ = t & 127, c_ = t >> 7;                                           \
      float ssum = 0.f;                                                        \
      _Pragma("unroll")                                                        \
      for (int w2 = 0; w2 < 8; ++w2)                                           \
        ssum += red8[(w2 * 32 + (p_ >> 2)) * 8 + (p_ & 3) * 2 + c_];           \
      xs[p_ * 2 + c_] += ssum * (1.f / NW);                                    \
      asm volatile("s_waitcnt lgkmcnt(0)" ::: "memory");                       \
      __builtin_amdgcn_s_barrier(); /* S3: xs settled for next phase A */      \
    }                                                                          \
  }

__global__ __launch_bounds__(TPB) void robbi_persistent(
    const float* __restrict__ y_re, const float* __restrict__ y_im,
    const float* __restrict__ H_re, const float* __restrict__ H_im,
    const float* __restrict__ Ew, const float* __restrict__ Eb,
    const float* __restrict__ Uw, const float* __restrict__ Ub,
    const float* __restrict__ Mw, const float* __restrict__ Mb,
    const float* __restrict__ thr_p, const int* __restrict__ niter_p,
    float* __restrict__ out, float* ws) {
  const int bid = blockIdx.x;
  const int t = threadIdx.x;
  // 8 members of a batch group share blockIdx % 8 (same-XCD under round-robin)
  const int xcd = bid & 7, gi = bid >> 3;
  const int b = xcd + 8 * (gi >> 3);   // batch 0..15
  const int m = gi & 7;                // member 0..7

  unsigned* wsu   = (unsigned*)ws;
  unsigned* root  = wsu;
  unsigned* leaf  = wsu + 32 * (xcd + 1);
  unsigned* gmax  = wsu + WS_GMAX;
  unsigned* grpc  = wsu + WS_GRP + 32 * b;
  float* part = ws + WS_PART;
  float* x0p  = ws + WS_X0P;
  float* tau  = ws + WS_TAU;

  __shared__ float wE[NW * 65], wU[NW * 65], wM[NW * 65];
  __shared__ float bE[NW], bU[NW], bM[NW];
  __shared__ float xs[PXM * 2];
  __shared__ float r2s[NW], tpl[NW], hts[NW];
  __shared__ float rs[2 * NW];
  __shared__ float red8[2048];
  __shared__ float ysr[2048], ysi[2048];
  __shared__ float axs[PXM];

  const float thr = *thr_p;
  const int niter = *niter_p;

  // ---- cache MLP weights (row-padded 65 -> conflict-free row reads) ----
  for (int i = t; i < NW * NW; i += TPB) {
    int r = i >> 6, c = i & 63;
    wE[r * 65 + c] = Ew[i]; wU[r * 65 + c] = Uw[i]; wM[r * 65 + c] = Mw[i];
  }
  if (t < NW) { bE[t] = Eb[t]; bU[t] = Ub[t]; bM[t] = Mb[t]; }

  const int wsub = t >> 5;        // 0..7
  const int g5   = t & 31;        // 0..31
  const int p4   = 4 * g5;        // pixel quad base within 128-px slice

  // ---- x0 stage 1: non-redundant partial GEMM over (kw-chunk, pixel-slice) ----
  {
    const int kwc = bid >> 3, ps = bid & 7;
    float ar[2][4], ai[2][4];
#pragma unroll
    for (int h = 0; h < 2; ++h)
#pragma unroll
      for (int j = 0; j < 4; ++j) { ar[h][j] = 0.f; ai[h][j] = 0.f; }
    for (int slab = 0; slab < 32; ++slab) {
      const int kw0 = kwc * 4096 + slab * 128;
      for (int e = t; e < 2048; e += TPB) {
        int bb = e >> 7, j = e & 127;
        ysr[e] = y_re[bb * NVIS_ + kw0 + j];
        ysi[e] = y_im[bb * NVIS_ + kw0 + j];
      }
      __syncthreads();
      for (int j = 0; j < 128; ++j) {
        const size_t off = (size_t)(kw0 + j) * NPX + ps * PXM + p4;
        float4 h4r = *(const float4*)(H_re + off);
        float4 h4i = *(const float4*)(H_im + off);
#pragma unroll
        for (int h = 0; h < 2; ++h) {
          int bb = wsub + 8 * h;
          float yr = ysr[bb * 128 + j], yi = ysi[bb * 128 + j];
          ar[h][0] += yr * h4r.x - yi * h4i.x; ai[h][0] += yr * h4i.x + yi * h4r.x;
          ar[h][1] += yr * h4r.y - yi * h4i.y; ai[h][1] += yr * h4i.y + yi * h4r.y;
          ar[h][2] += yr * h4r.z - yi * h4i.z; ai[h][2] += yr * h4i.z + yi * h4r.z;
          ar[h][3] += yr * h4r.w - yi * h4i.w; ai[h][3] += yr * h4i.w + yi * h4r.w;
        }
      }
      __syncthreads();
    }
#pragma unroll
    for (int h = 0; h < 2; ++h) {
      int bb = wsub + 8 * h;
#pragma unroll
      for (int j = 0; j < 4; ++j) {
        float* pp = x0p + ((size_t)(bid * NB + bb) * PXM + p4 + j) * 2;
        AG_STF(pp, ar[h][j]); AG_STF(pp + 1, ai[h][j]);
      }
    }
  }
  gbar_all(root, leaf, 1);

  // ---- x0 stage 2: reduce the 16 kw-chunks for this member's slice ----
  {
    int p = t & 127, c = t >> 7;
    float s = 0.f;
    for (int kwc = 0; kwc < 16; ++kwc)
      s += AG_LDF(x0p + ((size_t)((kwc * 8 + m) * NB + b) * PXM + p) * 2 + c);
    xs[p * 2 + c] = s;
  }
  __syncthreads();

  if (niter <= 0) {
    if (t < PXM) {
      float xr = xs[2 * t], xi = xs[2 * t + 1];
      out[b * NPX + m * PXM + t] = sqrtf(xr * xr + xi * xi);
    }
    return;
  }

  // ---- prologue: H tile for k=0 into slot A; y/tau prefetch for k=0 ----
  float4 hrA[8], hiA[8], hrB[8], hiB[8];
  {
    const size_t rb0 = (size_t)(0 * NW + wsub) * NPX + m * PXM + p4;
#pragma unroll
    for (int i = 0; i < 8; ++i) {
      hrA[i] = *(const float4*)(H_re + rb0 + (size_t)i * 8 * NPX);
      hiA[i] = *(const float4*)(H_im + rb0 + (size_t)i * 8 * NPX);
    }
  }
  float ypr_r = 0.f, ypr_i = 0.f, tpr = 0.f;
  if (t < 64) {
    ypr_r = y_re[b * NVIS_ + t];
    ypr_i = y_im[b * NVIS_ + t];
    tpr = 0.f;   // iter 0 uses tps=0 (guarded in STEP_BODY)
  }

  for (int iter = 0; iter < niter; ++iter) {
    for (int k = 0; k < NK; k += 2) {
      STEP_BODY(k,     hrA, hiA, hrB, hiB)
      STEP_BODY(k + 1, hrB, hiB, hrA, hiA)
    }

    // ---- global soft-threshold ----
    {
      float ax = 0.f;
      int p = t & 127;
      if (t < PXM) {
        float xr = xs[2 * p], xi = xs[2 * p + 1];
        ax = sqrtf(xr * xr + xi * xi);
        axs[p] = ax;
      }
      __syncthreads();
      for (int off = 64; off > 0; off >>= 1) {
        if (t < off) axs[t] = fmaxf(axs[t], axs[t + off]);
        __syncthreads();
      }
      if (t == 0)
        __hip_atomic_fetch_max(gmax + iter, __float_as_uint(axs[0]),
                               __ATOMIC_RELAXED, __HIP_MEMORY_SCOPE_AGENT);
      gbar_all(root, leaf, 2 + iter);
      float gm = __uint_as_float(__hip_atomic_load(gmax + iter, __ATOMIC_RELAXED,
                                                   __HIP_MEMORY_SCOPE_AGENT));
      if (t < PXM) {
        float mag = fmaxf(ax - thr * gm, 0.f);
        float sc = (ax > 0.f) ? (mag / ax) : 0.f;
        xs[2 * p] *= sc; xs[2 * p + 1] *= sc;
        if (iter == niter - 1) out[b * NPX + m * PXM + p] = mag;
      }
      __syncthreads();
    }
  }
}

extern "C" void kernel_launch(void* const* d_in, const int* in_sizes, int n_in,
                              void* d_out, int out_size, void* d_ws, size_t ws_size,
                              hipStream_t stream) {
  const float* y_re = (const float*)d_in[0];
  const float* y_im = (const float*)d_in[1];
  const float* H_re = (const float*)d_in[2];
  const float* H_im = (const float*)d_in[3];
  const float* Ew   = (const float*)d_in[4];
  const float* Eb   = (const float*)d_in[5];
  const float* Uw   = (const float*)d_in[6];
  const float* Ub   = (const float*)d_in[7];
  const float* Mw   = (const float*)d_in[8];
  const float* Mb   = (const float*)d_in[9];
  const float* thr  = (const float*)d_in[10];
  const int*  niter = (const int*)d_in[11];

  robbi_init<<<1, 256, 0, stream>>>((unsigned*)d_ws);
  robbi_persistent<<<NWG, TPB, 0, stream>>>(
      y_re, y_im, H_re, H_im, Ew, Eb, Uw, Ub, Mw, Mb, thr, niter,
      (float*)d_out, (float*)d_ws);
}